// Round 1
// baseline (342.134 us; speedup 1.0000x reference)
//
#include <hip/hip_runtime.h>

#define T_TOK 262144
#define D_IN 128
#define D_H 256
#define D_OUT 128
#define N_SETS 8192

typedef short short8 __attribute__((ext_vector_type(8)));
typedef float floatx4 __attribute__((ext_vector_type(4)));

__device__ inline unsigned short f32_bf16(float f) {
    unsigned int u = __float_as_uint(f);
    u += 0x7FFFu + ((u >> 16) & 1u);   // round-to-nearest-even
    return (unsigned short)(u >> 16);
}

// Swizzle W1 [128,256] and W2 [256,128] (row-major [k][n], fp32) into bf16
// MFMA B-fragment order: frag f -> 64 lanes x 8 bf16 contiguous, where lane l
// holds B[k = c*32 + (l>>4)*8 + j][n = nt*16 + (l&15)].
__global__ void prep_kernel(const float* __restrict__ W1, const float* __restrict__ W2,
                            unsigned short* __restrict__ W1s, unsigned short* __restrict__ W2s) {
    int t = blockIdx.x * 256 + threadIdx.x;
    int l = t & 63;
    int f = (t >> 6) & 63;
    int q = l >> 4, r = l & 15;
    if (t < 4096) {                      // W1: 16 n-tiles x 4 k-chunks
        int nt = f >> 2, c = f & 3;
        int k0 = c * 32 + q * 8, n = nt * 16 + r;
        unsigned short v[8];
#pragma unroll
        for (int j = 0; j < 8; j++) v[j] = f32_bf16(W1[(k0 + j) * D_H + n]);
#pragma unroll
        for (int j = 0; j < 8; j++) W1s[f * 512 + l * 8 + j] = v[j];
    } else if (t < 8192) {               // W2: 8 n-tiles x 8 k-chunks
        int nt = f >> 3, c = f & 7;
        int k0 = c * 32 + q * 8, n = nt * 16 + r;
        unsigned short v[8];
#pragma unroll
        for (int j = 0; j < 8; j++) v[j] = f32_bf16(W2[(k0 + j) * D_OUT + n]);
#pragma unroll
        for (int j = 0; j < 8; j++) W2s[f * 512 + l * 8 + j] = v[j];
    }
}

__global__ void zero_kernel(float4* __restrict__ out4, float4* __restrict__ cnt4) {
    int i = blockIdx.x * 256 + threadIdx.x;
    float4 z = make_float4(0.f, 0.f, 0.f, 0.f);
    if (i < 262144) out4[i] = z;             // out: 8192*128 floats
    else if (i < 264192) cnt4[i - 262144] = z; // counts: 8192 floats
}

__global__ __launch_bounds__(256) void ds_main(
    const float* __restrict__ x, const int* __restrict__ seg,
    const unsigned short* __restrict__ W1s, const float* __restrict__ b1,
    const unsigned short* __restrict__ W2s, const float* __restrict__ b2,
    float* __restrict__ out, float* __restrict__ counts)
{
    // h1 (bf16 [64][264]) and h2 (fp32 [64][132]) share the same 33792 bytes;
    // row slabs are wave-private, barrier protects the type overlay.
    __shared__ unsigned char smraw[64 * 264 * 2];
    unsigned short* h1 = (unsigned short*)smraw;
    float* h2 = (float*)smraw;
    __shared__ int sseg[64];

    const int tid = threadIdx.x;
    const int wave = tid >> 6, lane = tid & 63;
    const int r = lane & 15, q = lane >> 4;
    const int tile = blockIdx.x;

    if (tid < 64) sseg[tid] = seg[tile * 64 + tid];

    // ---- load x A-fragments: A[m=lane&15][k=(lane>>4)*8+j], bf16 ----
    const int mrow = tile * 64 + wave * 16 + r;
    const float* xp = x + (size_t)mrow * D_IN + q * 8;
    short8 a1[4];
#pragma unroll
    for (int c = 0; c < 4; c++) {
        float4 v0 = *(const float4*)(xp + c * 32);
        float4 v1 = *(const float4*)(xp + c * 32 + 4);
        short8 a;
        a[0] = (short)f32_bf16(v0.x); a[1] = (short)f32_bf16(v0.y);
        a[2] = (short)f32_bf16(v0.z); a[3] = (short)f32_bf16(v0.w);
        a[4] = (short)f32_bf16(v1.x); a[5] = (short)f32_bf16(v1.y);
        a[6] = (short)f32_bf16(v1.z); a[7] = (short)f32_bf16(v1.w);
        a1[c] = a;
    }

    // ---- layer 1: h1 = relu(x@W1 + b1) -> LDS bf16 ----
#pragma unroll
    for (int nt = 0; nt < 16; nt++) {
        floatx4 acc = {0.f, 0.f, 0.f, 0.f};
#pragma unroll
        for (int c = 0; c < 4; c++) {
            short8 b = *(const short8*)(W1s + (nt * 4 + c) * 512 + lane * 8);
            acc = __builtin_amdgcn_mfma_f32_16x16x32_bf16(a1[c], b, acc, 0, 0, 0);
        }
        float bias = b1[nt * 16 + r];
#pragma unroll
        for (int i = 0; i < 4; i++) {
            float v = fmaxf(acc[i] + bias, 0.f);
            h1[(wave * 16 + q * 4 + i) * 264 + nt * 16 + r] = f32_bf16(v);
        }
    }

    // ---- layer-2 A-fragments from own rows (wave-private, no barrier) ----
    short8 a2[8];
#pragma unroll
    for (int kc = 0; kc < 8; kc++)
        a2[kc] = *(const short8*)(h1 + (wave * 16 + r) * 264 + kc * 32 + q * 8);

    __syncthreads();   // h1 fully consumed before h2 overlays the bytes

    // ---- layer 2: h2 = relu(h1@W2 + b2) -> LDS fp32 ----
#pragma unroll
    for (int nt = 0; nt < 8; nt++) {
        floatx4 acc = {0.f, 0.f, 0.f, 0.f};
#pragma unroll
        for (int kc = 0; kc < 8; kc++) {
            short8 b = *(const short8*)(W2s + (nt * 8 + kc) * 512 + lane * 8);
            acc = __builtin_amdgcn_mfma_f32_16x16x32_bf16(a2[kc], b, acc, 0, 0, 0);
        }
        float bias = b2[nt * 16 + r];
#pragma unroll
        for (int i = 0; i < 4; i++) {
            float v = fmaxf(acc[i] + bias, 0.f);
            h2[(wave * 16 + q * 4 + i) * 132 + nt * 16 + r] = v;
        }
    }
    __syncthreads();

    // ---- per-tile segment counts (sorted ids -> runs) ----
    if (tid < 64) {
        int s = sseg[tid];
        if (tid == 0 || sseg[tid - 1] != s) {
            int len = 1;
            for (int u = tid + 1; u < 64 && sseg[u] == s; ++u) ++len;
            atomicAdd(&counts[s], (float)len);
        }
    }

    // ---- segment sums: thread owns one column over half the tile ----
    {
        const int c = tid & 127;
        const int t0 = (tid >> 7) * 32;
        int cur = sseg[t0];
        float sum = 0.f;
        for (int t2 = t0; t2 < t0 + 32; ++t2) {
            int s = sseg[t2];
            float v = h2[t2 * 132 + c];
            if (s != cur) {
                atomicAdd(&out[(size_t)cur * D_OUT + c], sum);
                sum = 0.f; cur = s;
            }
            sum += v;
        }
        atomicAdd(&out[(size_t)cur * D_OUT + c], sum);
    }
}

__global__ void div_kernel(float4* __restrict__ out4, const float* __restrict__ counts) {
    int i = blockIdx.x * 256 + threadIdx.x;   // 262144 float4s, 32 per row
    float inv = 1.f / fmaxf(counts[i >> 5], 1.f);
    float4 v = out4[i];
    v.x *= inv; v.y *= inv; v.z *= inv; v.w *= inv;
    out4[i] = v;
}

extern "C" void kernel_launch(void* const* d_in, const int* in_sizes, int n_in,
                              void* d_out, int out_size, void* d_ws, size_t ws_size,
                              hipStream_t stream) {
    const float* x  = (const float*)d_in[0];
    const int* seg  = (const int*)d_in[1];
    const float* W1 = (const float*)d_in[3];
    const float* b1 = (const float*)d_in[4];
    const float* W2 = (const float*)d_in[5];
    const float* b2 = (const float*)d_in[6];
    float* out = (float*)d_out;

    float* counts         = (float*)d_ws;                              // 32 KB
    unsigned short* W1s   = (unsigned short*)((char*)d_ws + 32768);    // 64 KB
    unsigned short* W2s   = (unsigned short*)((char*)d_ws + 32768 + 65536); // 64 KB

    hipLaunchKernelGGL(prep_kernel, dim3(32), dim3(256), 0, stream, W1, W2, W1s, W2s);
    hipLaunchKernelGGL(zero_kernel, dim3(1032), dim3(256), 0, stream,
                       (float4*)out, (float4*)counts);
    hipLaunchKernelGGL(ds_main, dim3(4096), dim3(256), 0, stream,
                       x, seg, W1s, b1, W2s, b2, out, counts);
    hipLaunchKernelGGL(div_kernel, dim3(1024), dim3(256), 0, stream,
                       (float4*)out, counts);
}

// Round 2
// 309.122 us; speedup vs baseline: 1.1068x; 1.1068x over previous
//
#include <hip/hip_runtime.h>

#define D_IN 128
#define D_H 256
#define D_OUT 128
#define N_SETS 8192

typedef short short8 __attribute__((ext_vector_type(8)));
typedef float floatx4 __attribute__((ext_vector_type(4)));

__device__ inline unsigned short f32_bf16(float f) {
    unsigned int u = __float_as_uint(f);
    u += 0x7FFFu + ((u >> 16) & 1u);   // round-to-nearest-even
    return (unsigned short)(u >> 16);
}

// Swizzle W1 [128,256] and W2 [256,128] (row-major [k][n], fp32) into bf16
// MFMA B-fragment order: frag f -> 64 lanes x 8 bf16 contiguous, where lane l
// holds B[k = c*32 + (l>>4)*8 + j][n = nt*16 + (l&15)].
__global__ void prep_kernel(const float* __restrict__ W1, const float* __restrict__ W2,
                            unsigned short* __restrict__ W1s, unsigned short* __restrict__ W2s) {
    int t = blockIdx.x * 256 + threadIdx.x;
    int l = t & 63;
    int f = (t >> 6) & 63;
    int q = l >> 4, r = l & 15;
    if (t < 4096) {                      // W1: 16 n-tiles x 4 k-chunks
        int nt = f >> 2, c = f & 3;
        int k0 = c * 32 + q * 8, n = nt * 16 + r;
        unsigned short v[8];
#pragma unroll
        for (int j = 0; j < 8; j++) v[j] = f32_bf16(W1[(k0 + j) * D_H + n]);
#pragma unroll
        for (int j = 0; j < 8; j++) W1s[f * 512 + l * 8 + j] = v[j];
    } else if (t < 8192) {               // W2: 8 n-tiles x 8 k-chunks
        int nt = f >> 3, c = f & 7;
        int k0 = c * 32 + q * 8, n = nt * 16 + r;
        unsigned short v[8];
#pragma unroll
        for (int j = 0; j < 8; j++) v[j] = f32_bf16(W2[(k0 + j) * D_OUT + n]);
#pragma unroll
        for (int j = 0; j < 8; j++) W2s[f * 512 + l * 8 + j] = v[j];
    }
}

__global__ void zero_kernel(float4* __restrict__ out4, float4* __restrict__ cnt4) {
    int i = blockIdx.x * 256 + threadIdx.x;
    float4 z = make_float4(0.f, 0.f, 0.f, 0.f);
    if (i < 262144) out4[i] = z;               // out: 8192*128 floats
    else if (i < 264192) cnt4[i - 262144] = z; // counts: 8192 floats
}

// Block = 256 thr (4 waves), 256 tokens. Each wave owns 64 tokens (4 m-tiles),
// reusing every weight B-frag load across 4 MFMAs. Layer1->Layer2 fused per
// 32-wide k-chunk through a wave-private LDS slab (no barriers: DS pipe is
// in-order within a wave). Layer2 acc lives in 128 regs across the k loop.
__global__ __launch_bounds__(256, 2) void ds_main(
    const float* __restrict__ x, const int* __restrict__ seg,
    const unsigned short* __restrict__ W1s, const float* __restrict__ b1,
    const unsigned short* __restrict__ W2s, const float* __restrict__ b2,
    float* __restrict__ out, float* __restrict__ counts)
{
    __shared__ unsigned short slab[4][64 * 40];  // per-wave h1 chunk [64 tok][40 cols] bf16 (uses 32)
    __shared__ float h2s[4][16 * 68];            // per-wave h2 chunk [16 cols][68 tok] fp32 (uses 64)
    __shared__ int sseg[256];

    const int tid = threadIdx.x;
    const int wave = tid >> 6, lane = tid & 63;
    const int r = lane & 15, q = lane >> 4;
    const int base = blockIdx.x * 256;
    const int wbase = base + wave * 64;

    sseg[tid] = seg[base + tid];
    __syncthreads();   // only barrier: sseg visibility across waves

    // ---- x A-frags: A[m = lane&15][k = (lane>>4)*8 + j], 4 m-tiles x 4 k-chunks ----
    short8 a1[4][4];
#pragma unroll
    for (int mt = 0; mt < 4; mt++) {
        const float* xp = x + (size_t)(wbase + mt * 16 + r) * D_IN + q * 8;
#pragma unroll
        for (int c = 0; c < 4; c++) {
            float4 v0 = *(const float4*)(xp + c * 32);
            float4 v1 = *(const float4*)(xp + c * 32 + 4);
            short8 a;
            a[0] = (short)f32_bf16(v0.x); a[1] = (short)f32_bf16(v0.y);
            a[2] = (short)f32_bf16(v0.z); a[3] = (short)f32_bf16(v0.w);
            a[4] = (short)f32_bf16(v1.x); a[5] = (short)f32_bf16(v1.y);
            a[6] = (short)f32_bf16(v1.z); a[7] = (short)f32_bf16(v1.w);
            a1[mt][c] = a;
        }
    }

    floatx4 acc2[8][4];
#pragma unroll
    for (int i = 0; i < 8; i++)
#pragma unroll
        for (int j = 0; j < 4; j++) acc2[i][j] = (floatx4){0.f, 0.f, 0.f, 0.f};

    unsigned short* myslab = slab[wave];

#pragma unroll
    for (int kc = 0; kc < 8; kc++) {
        // layer 1: produce h1 cols [kc*32, kc*32+32) for all 64 tokens
#pragma unroll
        for (int t = 0; t < 2; t++) {
            const int nt = kc * 2 + t;
            floatx4 acc1[4];
#pragma unroll
            for (int mt = 0; mt < 4; mt++) acc1[mt] = (floatx4){0.f, 0.f, 0.f, 0.f};
#pragma unroll
            for (int c = 0; c < 4; c++) {
                short8 bf = *(const short8*)(W1s + (nt * 4 + c) * 512 + lane * 8);
#pragma unroll
                for (int mt = 0; mt < 4; mt++)
                    acc1[mt] = __builtin_amdgcn_mfma_f32_16x16x32_bf16(a1[mt][c], bf, acc1[mt], 0, 0, 0);
            }
            const float bias = b1[nt * 16 + r];
            // C/D layout: col = lane&15 (= r), rows = q*4 + i within each m-tile
#pragma unroll
            for (int mt = 0; mt < 4; mt++)
#pragma unroll
                for (int i = 0; i < 4; i++) {
                    float v = fmaxf(acc1[mt][i] + bias, 0.f);
                    myslab[(mt * 16 + q * 4 + i) * 40 + t * 16 + r] = f32_bf16(v);
                }
        }
        // layer-2 A-frags straight back out of the wave-private slab
        short8 a2[4];
#pragma unroll
        for (int mt = 0; mt < 4; mt++)
            a2[mt] = *(const short8*)(myslab + (mt * 16 + r) * 40 + q * 8);
        // layer 2: accumulate all 8 n-tiles for this k-chunk
#pragma unroll
        for (int nt2 = 0; nt2 < 8; nt2++) {
            short8 bw = *(const short8*)(W2s + (nt2 * 8 + kc) * 512 + lane * 8);
#pragma unroll
            for (int mt = 0; mt < 4; mt++)
                acc2[nt2][mt] = __builtin_amdgcn_mfma_f32_16x16x32_bf16(a2[mt], bw, acc2[nt2][mt], 0, 0, 0);
        }
    }

    // ---- per-block segment counts (sorted ids -> run heads) ----
    {
        int s = sseg[tid];
        if (tid == 0 || sseg[tid - 1] != s) {
            int len = 1;
            for (int u = tid + 1; u < 256 && sseg[u] == s; ++u) ++len;
            atomicAdd(&counts[s], (float)len);
        }
    }

    // ---- epilogue: bias+relu, LDS transpose chunk, segmented atomic sums ----
    float* myh2 = h2s[wave];
#pragma unroll
    for (int nt2 = 0; nt2 < 8; nt2++) {
        const float bias = b2[nt2 * 16 + r];
#pragma unroll
        for (int mt = 0; mt < 4; mt++) {
            floatx4 v;
#pragma unroll
            for (int i = 0; i < 4; i++) v[i] = fmaxf(acc2[nt2][mt][i] + bias, 0.f);
            *(floatx4*)(myh2 + r * 68 + mt * 16 + q * 4) = v;  // [col r][4 consecutive tokens]
        }
        // lane (q,r): sweep col r, tokens q*16 .. q*16+15 (wave-private, DS in-order)
        const int col = nt2 * 16 + r;
        const int t0 = q * 16;
        int cur = sseg[wave * 64 + t0];
        float sum = 0.f;
#pragma unroll
        for (int g = 0; g < 4; g++) {
            floatx4 v = *(const floatx4*)(myh2 + r * 68 + t0 + g * 4);
#pragma unroll
            for (int e = 0; e < 4; e++) {
                int s = sseg[wave * 64 + t0 + g * 4 + e];
                if (s != cur) {
                    atomicAdd(&out[(size_t)cur * D_OUT + col], sum);
                    sum = 0.f; cur = s;
                }
                sum += v[e];
            }
        }
        atomicAdd(&out[(size_t)cur * D_OUT + col], sum);
    }
}

__global__ void div_kernel(float4* __restrict__ out4, const float* __restrict__ counts) {
    int i = blockIdx.x * 256 + threadIdx.x;   // 262144 float4s, 32 per row
    float inv = 1.f / fmaxf(counts[i >> 5], 1.f);
    float4 v = out4[i];
    v.x *= inv; v.y *= inv; v.z *= inv; v.w *= inv;
    out4[i] = v;
}

extern "C" void kernel_launch(void* const* d_in, const int* in_sizes, int n_in,
                              void* d_out, int out_size, void* d_ws, size_t ws_size,
                              hipStream_t stream) {
    const float* x  = (const float*)d_in[0];
    const int* seg  = (const int*)d_in[1];
    const float* W1 = (const float*)d_in[3];
    const float* b1 = (const float*)d_in[4];
    const float* W2 = (const float*)d_in[5];
    const float* b2 = (const float*)d_in[6];
    float* out = (float*)d_out;

    float* counts       = (float*)d_ws;                                   // 32 KB
    unsigned short* W1s = (unsigned short*)((char*)d_ws + 32768);         // 64 KB
    unsigned short* W2s = (unsigned short*)((char*)d_ws + 32768 + 65536); // 64 KB

    hipLaunchKernelGGL(prep_kernel, dim3(32), dim3(256), 0, stream, W1, W2, W1s, W2s);
    hipLaunchKernelGGL(zero_kernel, dim3(1032), dim3(256), 0, stream,
                       (float4*)out, (float4*)counts);
    hipLaunchKernelGGL(ds_main, dim3(1024), dim3(256), 0, stream,
                       x, seg, W1s, b1, W2s, b2, out, counts);
    hipLaunchKernelGGL(div_kernel, dim3(1024), dim3(256), 0, stream,
                       (float4*)out, counts);
}